// Round 13
// baseline (31.376 us; speedup 1.0000x reference)
//
#include <hip/hip_runtime.h>

#define KP 137
#define SS 512
#define BB 128
#define STRIP 8
#define NSTRIP (SS / STRIP)          // 64 strips per batch
#define NWAVE (BB * NSTRIP)          // 8192 waves
#define THREADS 128                  // 2 independent waves per block
#define NBLK (NWAVE / 2)             // 4096 blocks

// ZERO-SHUFFLE mapping: lane l owns bone PAIR(s) via overlapping loads.
//   A: pair l      (l=0..63)  pred float4 @ kp 2l   -> kps (l, l+1) wait no:
//      pred float4 @ float-offset 2l = (x_l, y_l, x_{l+1}, y_{l+1})
//      target float2 @ k=l          = (t_l, t_{l+1}) per plane
//   B: pair 64+l   (l=0..63), same with k=64+l
//   C: pair 128+l  (l=0..7),  same with k=128+l   (l=7 reads floats up to
//      273 (pred) / 136 (target) — exactly in-bounds)
// Pose (each kp once, vs target row s+1):
//   A lane l: kp l; lane 63 additionally kp 64 (second elems)
//   B lane l: kp 65+l (second elems)  -> 65..128
//   C lane l: kp 129+l (second elems) -> 129..136
// Bone (pair k, vs target row s): in-lane: (e_{k+1}-e_k) from float4 halves.
// No __shfl in the hot loop (ds_bpermute suspected as the structure-invariant
// ~24us plateau: L3-warm replays = cold speed, VALUBusy 11%, 7 structures).
// No __threadfence/fused finisher (r5/r6/r9: collapses to ~200 GB/s).

__global__ __launch_bounds__(THREADS) void t2p_main(
    const float* __restrict__ pred,      // [B,S,2K]
    const float* __restrict__ tgt,       // [B,2,S,K]
    const int*   __restrict__ tlen,      // [B]
    float2* __restrict__ partials)       // [NBLK]
{
    __shared__ float2 wsum[2];

    const int t    = threadIdx.x;
    const int lane = t & 63;
    const int wid  = t >> 6;
    const int w    = blockIdx.x * 2 + wid;   // global wave id, 0..8191
    const int b    = w >> 6;                 // NSTRIP = 64 strips per batch
    const int s0   = (w & (NSTRIP - 1)) * STRIP;
    const int len  = tlen[b];

    float pose = 0.f, bone = 0.f;

    if (s0 < len) {                          // wave-uniform; no barriers inside
        const int send = (len < s0 + STRIP) ? len : (s0 + STRIP);
        const float* txp = tgt + (size_t)(2 * b) * SS * KP;   // x plane
        const float* typ = txp + (size_t)SS * KP;             // y plane
        const float* pp  = pred + (size_t)b * SS * (2 * KP);

        const bool lc = (lane < 8);
        const int kA = lane;                 // pair/kp base, sub-batch A
        const int kB = 64 + lane;            // sub-batch B
        const int kC = lc ? (128 + lane) : 128;  // sub-batch C (clamped, masked)

        // rolling same-row target (row s0): float2 per (plane, sub-batch)
        float2 x0A, x0B, x0C, y0A, y0B, y0C;
        {
            const float* r = txp + s0 * KP;
            const float* q = typ + s0 * KP;
            x0A = *(const float2*)(r + kA); y0A = *(const float2*)(q + kA);
            x0B = *(const float2*)(r + kB); y0B = *(const float2*)(q + kB);
            x0C = lc ? *(const float2*)(r + kC) : make_float2(0.f, 0.f);
            y0C = lc ? *(const float2*)(q + kC) : make_float2(0.f, 0.f);
        }

        for (int s = s0; s < send; ++s) {
            // ---- loads: 3 pred float4 + 6 target float2 (C-group 8-lane) ----
            const float* prow = pp + (size_t)s * (2 * KP);
            float4 pA = *(const float4*)(prow + 2 * kA);   // x_k,y_k,x_k1,y_k1
            float4 pB = *(const float4*)(prow + 2 * kB);
            float4 pC = lc ? *(const float4*)(prow + 2 * kC)
                           : make_float4(0.f, 0.f, 0.f, 0.f);

            const int sn = (s + 1 < SS) ? s + 1 : SS - 1;  // clamp; masked
            const float* r = txp + sn * KP;
            const float* q = typ + sn * KP;
            float2 x1A = *(const float2*)(r + kA), y1A = *(const float2*)(q + kA);
            float2 x1B = *(const float2*)(r + kB), y1B = *(const float2*)(q + kB);
            float2 x1C = lc ? *(const float2*)(r + kC) : make_float2(0.f, 0.f);
            float2 y1C = lc ? *(const float2*)(q + kC) : make_float2(0.f, 0.f);

            // ---- pose: pred row s vs target row s+1, each kp once ----
            if (s < len - 1) {               // wave-uniform
                float acc = fabsf(pA.x - x1A.x) + fabsf(pA.y - y1A.x); // kp l
                if (lane == 63)              // kp 64 (A second elems)
                    acc += fabsf(pA.z - x1A.y) + fabsf(pA.w - y1A.y);
                acc += fabsf(pB.z - x1B.y) + fabsf(pB.w - y1B.y);      // kp 65+l
                if (lc)                      // kp 129+l
                    acc += fabsf(pC.z - x1C.y) + fabsf(pC.w - y1C.y);
                pose += acc;
            }

            // ---- bone: pair k in-lane, e = pred - target(row s) ----
            {
                float dx = (pA.z - x0A.y) - (pA.x - x0A.x);
                float dy = (pA.w - y0A.y) - (pA.y - y0A.x);
                float acc = dx * dx + dy * dy;                         // pair l
                dx = (pB.z - x0B.y) - (pB.x - x0B.x);
                dy = (pB.w - y0B.y) - (pB.y - y0B.x);
                acc += dx * dx + dy * dy;                              // 64+l
                if (lc) {
                    dx = (pC.z - x0C.y) - (pC.x - x0C.x);
                    dy = (pC.w - y0C.y) - (pC.y - y0C.x);
                    acc += dx * dx + dy * dy;                          // 128+l
                }
                bone += acc;
            }

            // roll: row s+1 target becomes next iteration's same-row target
            x0A = x1A; y0A = y1A; x0B = x1B; y0B = y1B; x0C = x1C; y0C = y1C;
        }
    }

    // per-wave reduce (epilogue only — 6 shfl per STRIP, not per row)
    for (int off = 32; off > 0; off >>= 1) {
        pose += __shfl_down(pose, off, 64);
        bone += __shfl_down(bone, off, 64);
    }
    if (lane == 0) wsum[wid] = make_float2(pose, bone);
    __syncthreads();
    if (t == 0) {
        partials[blockIdx.x] = make_float2(wsum[0].x + wsum[1].x,
                                           wsum[0].y + wsum[1].y);
    }
}

__global__ __launch_bounds__(1024) void t2p_final(
    const float2* __restrict__ partials,
    const int* __restrict__ tlen,
    float* __restrict__ out)
{
    const int t = threadIdx.x;
    float ps = 0.f, bs = 0.f;
    #pragma unroll
    for (int i = 0; i < NBLK / 1024; ++i) {      // 4 each
        float2 v = partials[t + i * 1024];
        ps += v.x; bs += v.y;
    }
    float pc = 0.f, mc = 0.f;
    if (t < BB) {
        int L = tlen[t];
        pc = (float)(L - 1);   // sum(pose_mask)
        mc = (float)L;         // sum(mask)
    }
    for (int off = 32; off > 0; off >>= 1) {
        ps += __shfl_down(ps, off, 64);
        bs += __shfl_down(bs, off, 64);
        pc += __shfl_down(pc, off, 64);
        mc += __shfl_down(mc, off, 64);
    }
    __shared__ float4 wsum[16];
    if ((t & 63) == 0) wsum[t >> 6] = make_float4(ps, bs, pc, mc);
    __syncthreads();
    if (t == 0) {
        float4 a = wsum[0];
        #pragma unroll
        for (int i = 1; i < 16; ++i) {
            a.x += wsum[i].x; a.y += wsum[i].y;
            a.z += wsum[i].z; a.w += wsum[i].w;
        }
        float pose_loss = a.x / (274.f * a.z);
        float bone_loss = (a.y * 0.5f) / ((136.f + 1e-8f) * a.w);
        out[0] = pose_loss + 0.1f * bone_loss;   // POSE_W=1, BONE_W=0.1
        out[1] = pose_loss;
        out[2] = bone_loss;
    }
}

extern "C" void kernel_launch(void* const* d_in, const int* in_sizes, int n_in,
                              void* d_out, int out_size, void* d_ws, size_t ws_size,
                              hipStream_t stream) {
    const float* pred = (const float*)d_in[0];   // [128,512,274] f32
    const float* tgt  = (const float*)d_in[1];   // [128,2,512,137] f32
    const int*   tlen = (const int*)d_in[2];     // [128] i32
    float* out = (float*)d_out;
    float2* partials = (float2*)d_ws;            // 4096 * 8 B = 32 KB

    t2p_main<<<NBLK, THREADS, 0, stream>>>(pred, tgt, tlen, partials);
    t2p_final<<<1, 1024, 0, stream>>>(partials, tlen, out);
}

// Round 15
// 25.599 us; speedup vs baseline: 1.2257x; 1.2257x over previous
//
#include <hip/hip_runtime.h>

#define KP 137
#define SS 512
#define BB 128
#define STRIP 4
#define NSTRIP (SS / STRIP)          // 128 strips per batch
#define NBLK (BB * NSTRIP)           // 16384 one-wave blocks

// r7 structure (best: 23.6us) + NON-TEMPORAL loads: every byte is read exactly
// once (target row s+1 -> s reuse is held in registers), so nt loads skip L1
// allocation. Theory: the 24us plateau across 9 structures tracks unique
// cache-line touches per CU (r13: 2x touches -> 2x time), i.e. an L1
// miss-handling throughput wall; nt routes the stream to the deeper TCC path.
// __builtin_nontemporal_load requires scalar/clang-vector types, so float2
// loads use ext_vector_type(2) (r14 compile fix).
// NOTE: no __threadfence/fused finisher (r5/r6/r9 collapse).

typedef float vfloat2 __attribute__((ext_vector_type(2)));

__device__ __forceinline__ float ntf(const float* p) {
    return __builtin_nontemporal_load(p);
}
__device__ __forceinline__ vfloat2 ntf2(const float* p) {
    return __builtin_nontemporal_load((const vfloat2*)p);
}

__global__ __launch_bounds__(64) void t2p_main(
    const float* __restrict__ pred,      // [B,S,2K]
    const float* __restrict__ tgt,       // [B,2,S,K]
    const int*   __restrict__ tlen,      // [B]
    float2* __restrict__ partials)       // [NBLK]
{
    const int lane = threadIdx.x;            // one wave per block
    const int w    = blockIdx.x;
    const int b    = w >> 7;                 // NSTRIP = 128 strips per batch
    const int s0   = (w & (NSTRIP - 1)) * STRIP;
    const int len  = tlen[b];

    float pose = 0.f, bone = 0.f;

    if (s0 < len) {
        const int send = (len < s0 + STRIP) ? len : (s0 + STRIP);
        const float* txp = tgt + (size_t)(2 * b) * SS * KP;   // x plane
        const float* typ = txp + (size_t)SS * KP;             // y plane
        const float* pp  = pred + (size_t)b * SS * (2 * KP);
        const bool lc = (lane <= 10);

        // rolling same-row target (row s0)
        float t0xa, t0xb, t0xc, t0ya, t0yb, t0yc;
        {
            const float* r = txp + s0 * KP;
            const float* q = typ + s0 * KP;
            t0xa = ntf(r + lane); t0xb = ntf(r + 63 + lane);
            t0xc = lc ? ntf(r + 126 + lane) : 0.f;
            t0ya = ntf(q + lane); t0yb = ntf(q + 63 + lane);
            t0yc = lc ? ntf(q + 126 + lane) : 0.f;
        }

        for (int s = s0; s < send; ++s) {
            const float* prow = pp + (size_t)s * (2 * KP);
            vfloat2 pa = ntf2(prow + 2 * lane);
            vfloat2 pb = ntf2(prow + 2 * (63 + lane));
            vfloat2 pc = lc ? ntf2(prow + 2 * (126 + lane)) : (vfloat2){0.f, 0.f};

            float t1xa = 0.f, t1xb = 0.f, t1xc = 0.f;
            float t1ya = 0.f, t1yb = 0.f, t1yc = 0.f;
            if (s + 1 < SS) {                 // uniform branch
                const float* r = txp + (s + 1) * KP;
                const float* q = typ + (s + 1) * KP;
                t1xa = ntf(r + lane); t1xb = ntf(r + 63 + lane);
                t1xc = lc ? ntf(r + 126 + lane) : 0.f;
                t1ya = ntf(q + lane); t1yb = ntf(q + 63 + lane);
                t1yc = lc ? ntf(q + 126 + lane) : 0.f;
            }

            // pose: each kp counted once
            if (s < len - 1) {                // wave-uniform
                float acc = fabsf(pa.x - t1xa) + fabsf(pa.y - t1ya);
                if (lane >= 1)       acc += fabsf(pb.x - t1xb) + fabsf(pb.y - t1yb);
                if (lane >= 1 && lc) acc += fabsf(pc.x - t1xc) + fabsf(pc.y - t1yc);
                pose += acc;
            }

            // e = pred - target (same row), bone via lane-shift
            float exa = pa.x - t0xa, eya = pa.y - t0ya;
            float exb = pb.x - t0xb, eyb = pb.y - t0yb;
            float exc = pc.x - t0xc, eyc = pc.y - t0yc;
            float nxa = __shfl_down(exa, 1, 64), nya = __shfl_down(eya, 1, 64);
            float nxb = __shfl_down(exb, 1, 64), nyb = __shfl_down(eyb, 1, 64);
            float nxc = __shfl_down(exc, 1, 64), nyc = __shfl_down(eyc, 1, 64);
            float acc = 0.f;
            if (lane < 63) {
                float dx = nxa - exa, dy = nya - eya; acc += dx * dx + dy * dy;
                float ex = nxb - exb, ey = nyb - eyb; acc += ex * ex + ey * ey;
            }
            if (lane < 10) {
                float dx = nxc - exc, dy = nyc - eyc; acc += dx * dx + dy * dy;
            }
            bone += acc;

            // roll: row s+1 target becomes next iteration's same-row target
            t0xa = t1xa; t0xb = t1xb; t0xc = t1xc;
            t0ya = t1ya; t0yb = t1yb; t0yc = t1yc;
        }
    }

    // wave reduce; no LDS, no barrier
    for (int off = 32; off > 0; off >>= 1) {
        pose += __shfl_down(pose, off, 64);
        bone += __shfl_down(bone, off, 64);
    }
    if (lane == 0) partials[w] = make_float2(pose, bone);
}

__global__ __launch_bounds__(1024) void t2p_final(
    const float2* __restrict__ partials,
    const int* __restrict__ tlen,
    float* __restrict__ out)
{
    const int t = threadIdx.x;
    float ps = 0.f, bs = 0.f;
    #pragma unroll
    for (int i = 0; i < NBLK / 1024; ++i) {      // 16 each
        float2 v = partials[t + i * 1024];
        ps += v.x; bs += v.y;
    }
    float pc = 0.f, mc = 0.f;
    if (t < BB) {
        int L = tlen[t];
        pc = (float)(L - 1);   // sum(pose_mask)
        mc = (float)L;         // sum(mask)
    }
    for (int off = 32; off > 0; off >>= 1) {
        ps += __shfl_down(ps, off, 64);
        bs += __shfl_down(bs, off, 64);
        pc += __shfl_down(pc, off, 64);
        mc += __shfl_down(mc, off, 64);
    }
    __shared__ float4 wsum[16];
    if ((t & 63) == 0) wsum[t >> 6] = make_float4(ps, bs, pc, mc);
    __syncthreads();
    if (t == 0) {
        float4 a = wsum[0];
        #pragma unroll
        for (int i = 1; i < 16; ++i) {
            a.x += wsum[i].x; a.y += wsum[i].y;
            a.z += wsum[i].z; a.w += wsum[i].w;
        }
        float pose_loss = a.x / (274.f * a.z);
        float bone_loss = (a.y * 0.5f) / ((136.f + 1e-8f) * a.w);
        out[0] = pose_loss + 0.1f * bone_loss;   // POSE_W=1, BONE_W=0.1
        out[1] = pose_loss;
        out[2] = bone_loss;
    }
}

extern "C" void kernel_launch(void* const* d_in, const int* in_sizes, int n_in,
                              void* d_out, int out_size, void* d_ws, size_t ws_size,
                              hipStream_t stream) {
    const float* pred = (const float*)d_in[0];   // [128,512,274] f32
    const float* tgt  = (const float*)d_in[1];   // [128,2,512,137] f32
    const int*   tlen = (const int*)d_in[2];     // [128] i32
    float* out = (float*)d_out;
    float2* partials = (float2*)d_ws;            // 16384 * 8 B = 128 KB

    t2p_main<<<NBLK, 64, 0, stream>>>(pred, tgt, tlen, partials);
    t2p_final<<<1, 1024, 0, stream>>>(partials, tlen, out);
}